// Round 1
// baseline (995.444 us; speedup 1.0000x reference)
//
#include <hip/hip_runtime.h>
#include <stdint.h>

// ---------------- problem constants ----------------
constexpr int   SEQ  = 8192;
constexpr int   NB   = 64;
constexpr int   ND   = 16;
constexpr float DT    = 0.01f;
constexpr float BETA  = 0.25f;
constexpr float GAMMA = 0.5f;
constexpr float C1 = (0.5f - BETA) * DT * DT;
constexpr float C2 = (1.0f - GAMMA) * DT;
constexpr float C3 = BETA * DT * DT;
constexpr float C4 = GAMMA * DT;
constexpr float E1 = C1 + C3 + DT * C4;   // up' = up + DT*vp + E1*acc
constexpr float E2 = C2 + C4;             // vp' = vp + E2*acc
constexpr float GDT  = GAMMA * DT;
constexpr float BDT2 = BETA * DT * DT;

constexpr int LCH = 4;        // scan chunk = 4 steps (was 16: warm-up ladder removed)
constexpr int NCH = 2048;     // chunks covering steps 1..8191 (last chunk has 3 steps)
constexpr size_t BSTRIDE = (size_t)SEQ * ND;
constexpr size_t UOFF = 0;
constexpr size_t VOFF = (size_t)NB * SEQ * ND;
constexpr size_t AOFF = 2 * VOFF;

// ws layout (float offsets). Total usage ~2.4 MB (shrunk vs previous 4.8 MB).
constexpr int WS_A1T   = 0;                    // 768: A1^T, A2^T, A3^T (j*16+d)
constexpr int WS_G4    = 768;                  // 1024 each, 32x32 row-major
constexpr int WS_G32   = 1792;
constexpr int WS_G256  = 2816;
constexpr int WS_G2048 = 3840;
constexpr int WS_P1    = 4864;                 // 2048: seed state entering step 1, [b*32+r]
constexpr int WS_T1    = 8192;                 // 256 * 2048
constexpr int WS_T2    = WS_T1 + 256 * 2048;   // 32  * 2048
constexpr int WS_T3    = WS_T2 + 32 * 2048;    // 4   * 2048

// 4-step chunk totals (up-sweep) -> chunk starts (down-sweep).
// Static __device__ buffer (16.8 MB): avoids any assumption about ws_size.
// Layout: [chunk][batch*32 + row], rows 0..15 = up, 16..31 = vp.
__device__ float g_cbuf[(size_t)NCH * 2048];

// =====================================================================
// Newmark step core: acc = A1*f - A3*up - A2*vp, matrices from LDS.
// All lanes read the same LDS address -> ds_read_b128 broadcast,
// conflict-free; compiler pipelines with fine lgkmcnt. This replaces the
// old per-step wave-uniform s_load reload (the 25k-cycle/step stall).
// =====================================================================
__device__ __forceinline__ void nm_acc(const float* __restrict__ sA,
                                       const float f[16], const float up[16],
                                       const float vp[16], float acc[16])
{
    #pragma unroll
    for (int d = 0; d < 16; ++d) acc[d] = 0.f;
    #pragma unroll
    for (int j = 0; j < 16; ++j) {
        const float fj = f[j];
        const float nu = -up[j];
        const float nv = -vp[j];
        #pragma unroll
        for (int q = 0; q < 4; ++q) {
            const float4 m1 = *(const float4*)(sA +       j*16 + 4*q);   // A1^T row j
            const float4 m2 = *(const float4*)(sA + 256 + j*16 + 4*q);   // A2^T row j
            const float4 m3 = *(const float4*)(sA + 512 + j*16 + 4*q);   // A3^T row j
            acc[4*q+0] = fmaf(m1.x, fj, acc[4*q+0]);
            acc[4*q+0] = fmaf(m3.x, nu, acc[4*q+0]);
            acc[4*q+0] = fmaf(m2.x, nv, acc[4*q+0]);
            acc[4*q+1] = fmaf(m1.y, fj, acc[4*q+1]);
            acc[4*q+1] = fmaf(m3.y, nu, acc[4*q+1]);
            acc[4*q+1] = fmaf(m2.y, nv, acc[4*q+1]);
            acc[4*q+2] = fmaf(m1.z, fj, acc[4*q+2]);
            acc[4*q+2] = fmaf(m3.z, nu, acc[4*q+2]);
            acc[4*q+2] = fmaf(m2.z, nv, acc[4*q+2]);
            acc[4*q+3] = fmaf(m1.w, fj, acc[4*q+3]);
            acc[4*q+3] = fmaf(m3.w, nu, acc[4*q+3]);
            acc[4*q+3] = fmaf(m2.w, nv, acc[4*q+3]);
        }
    }
}

__device__ __forceinline__ void nm_update(float up[16], float vp[16], const float acc[16])
{
    #pragma unroll
    for (int d = 0; d < 16; ++d) {
        up[d] = fmaf(DT, vp[d], up[d]);   // uses pre-update vp
        up[d] = fmaf(E1, acc[d], up[d]);
        vp[d] = fmaf(E2, acc[d], vp[d]);
    }
}

// =====================================================================
// K0: invert K_eff & M, A2/A3, G powers {4,32,256,2048}, p1 seed,
// step-0 outputs. One block, 512 threads.
// =====================================================================
__global__ __launch_bounds__(512) void setup_k(const float* __restrict__ F,
                                               const float* __restrict__ Mg,
                                               const float* __restrict__ Cg,
                                               const float* __restrict__ Kg,
                                               float* __restrict__ ws,
                                               float* __restrict__ out)
{
    __shared__ float sM[256], sC[256], sK[256];
    __shared__ float aug[16][33];
    __shared__ float A1s[256], A2s[256], A3s[256], Mis[256];
    __shared__ float bA[1024], bB[1024];
    const int tid = threadIdx.x;
    if (tid < 256) { sM[tid] = Mg[tid]; sC[tid] = Cg[tid]; sK[tid] = Kg[tid]; }
    __syncthreads();

    const int r = tid >> 5, c = tid & 31;
    {
        float v;
        if (c < 16) v = sM[r*16+c] + GDT * sC[r*16+c] + BDT2 * sK[r*16+c];
        else        v = (c - 16 == r) ? 1.f : 0.f;
        aug[r][c] = v;
    }
    __syncthreads();
    for (int kk = 0; kk < 16; ++kk) {
        float pv   = aug[kk][kk];
        float fr   = aug[r][kk];
        float akc  = aug[kk][c];
        float curv = aug[r][c];
        __syncthreads();
        float inv = 1.0f / pv;
        aug[r][c] = (r == kk) ? curv * inv : fmaf(-fr * inv, akc, curv);
        __syncthreads();
    }
    if (tid < 256) A1s[tid] = aug[tid >> 4][(tid & 15) + 16];
    __syncthreads();

    aug[r][c] = (c < 16) ? sM[r*16+c] : ((c - 16 == r) ? 1.f : 0.f);
    __syncthreads();
    for (int kk = 0; kk < 16; ++kk) {
        float pv   = aug[kk][kk];
        float fr   = aug[r][kk];
        float akc  = aug[kk][c];
        float curv = aug[r][c];
        __syncthreads();
        float inv = 1.0f / pv;
        aug[r][c] = (r == kk) ? curv * inv : fmaf(-fr * inv, akc, curv);
        __syncthreads();
    }
    if (tid < 256) Mis[tid] = aug[tid >> 4][(tid & 15) + 16];
    __syncthreads();

    if (tid < 256) {
        const int rr = tid >> 4, cc = tid & 15;
        float a2 = 0.f, a3 = 0.f;
        #pragma unroll
        for (int j = 0; j < 16; ++j) {
            const float a = A1s[rr*16+j];
            a2 = fmaf(a, sC[j*16+cc], a2);
            a3 = fmaf(a, sK[j*16+cc], a3);
        }
        A2s[tid] = a2; A3s[tid] = a3;
    }
    __syncthreads();

    // transposed matrices for the step kernels: ws[j*16+d] = A[d][j]
    if (tid < 256) {
        const int j = tid >> 4, d = tid & 15;
        ws[WS_A1T +       tid] = A1s[d*16+j];
        ws[WS_A1T + 256 + tid] = A2s[d*16+j];
        ws[WS_A1T + 512 + tid] = A3s[d*16+j];
    }
    // G (32x32 one-step state transfer), then repeated squaring.
    for (int idx = tid; idx < 1024; idx += 512) {
        const int i = idx >> 5, j = idx & 31;
        float v;
        if (i < 16) {
            if (j < 16) v = ((i == j) ? 1.f : 0.f) - E1 * A3s[i*16+j];
            else        v = ((i == j - 16) ? DT : 0.f) - E1 * A2s[i*16+(j-16)];
        } else {
            const int i2 = i - 16;
            if (j < 16) v = -E2 * A3s[i2*16+j];
            else        v = ((i2 == j - 16) ? 1.f : 0.f) - E2 * A2s[i2*16+(j-16)];
        }
        bA[idx] = v;
    }
    __syncthreads();
    // after s iterations: bA = G^(2^(s+1)); store G4, G32, G256, G2048
    for (int s = 0; s < 11; ++s) {
        for (int idx = tid; idx < 1024; idx += 512) {
            const int i = idx >> 5, j = idx & 31;
            float acc = 0.f;
            #pragma unroll
            for (int q = 0; q < 32; ++q) acc = fmaf(bA[i*32+q], bA[q*32+j], acc);
            bB[idx] = acc;
        }
        __syncthreads();
        for (int idx = tid; idx < 1024; idx += 512) bA[idx] = bB[idx];
        __syncthreads();
        if (s == 1) for (int idx = tid; idx < 1024; idx += 512) ws[WS_G4   + idx] = bA[idx];
        if (s == 4) for (int idx = tid; idx < 1024; idx += 512) ws[WS_G32  + idx] = bA[idx];
        if (s == 7) for (int idx = tid; idx < 1024; idx += 512) ws[WS_G256 + idx] = bA[idx];
    }
    for (int idx = tid; idx < 1024; idx += 512) ws[WS_G2048 + idx] = bA[idx];

    // step-0 outputs + p1 seed (state entering step 1): up=C1*a0, vp=C2*a0
    for (int t = tid; t < 1024; t += 512) {
        const int b = t >> 4, d = t & 15;
        float s0 = 0.f;
        #pragma unroll
        for (int j = 0; j < 16; ++j) s0 = fmaf(Mis[d*16+j], F[(size_t)b * BSTRIDE + j], s0);
        out[UOFF + (size_t)b * BSTRIDE + d] = 0.f;
        out[VOFF + (size_t)b * BSTRIDE + d] = 0.f;
        out[AOFF + (size_t)b * BSTRIDE + d] = s0;
        ws[WS_P1 + b*32 + d]      = C1 * s0;
        ws[WS_P1 + b*32 + 16 + d] = C2 * s0;
    }
}

// =====================================================================
// K1: per-chunk (4-step) zero-init totals. 512 blocks x 256 thr.
// Wave w owns chunk 4*blk+w; lane = batch. F direct-to-register
// (prefetched one step ahead); matrices via LDS broadcast.
// One barrier total (sA fill); waves fully independent after that.
// =====================================================================
__global__ __launch_bounds__(256, 2) void phase1_k(const float* __restrict__ F,
                                                   const float* __restrict__ ws)
{
    alignas(16) __shared__ float sA[768];
    const int tid = threadIdx.x;
    for (int i = tid; i < 768; i += 256) sA[i] = ws[WS_A1T + i];
    __syncthreads();

    const int w = tid >> 6, l = tid & 63;
    const int kc = blockIdx.x * 4 + w;
    const int s0 = LCH * kc + 1;
    const int nst = min(LCH, SEQ - s0);          // last chunk: 3 steps
    const float* Fb = F + (size_t)l * BSTRIDE;

    float up[16], vp[16], acc[16];
    #pragma unroll
    for (int d = 0; d < 16; ++d) { up[d] = 0.f; vp[d] = 0.f; }

    float4 f4[4];
    #pragma unroll
    for (int q = 0; q < 4; ++q) f4[q] = *(const float4*)(Fb + (size_t)s0 * ND + 4*q);

    for (int i = 0; i < nst; ++i) {
        float f[16];
        #pragma unroll
        for (int q = 0; q < 4; ++q) {
            f[4*q+0] = f4[q].x; f[4*q+1] = f4[q].y; f[4*q+2] = f4[q].z; f[4*q+3] = f4[q].w;
        }
        const int sn = (i + 1 < nst) ? (s0 + i + 1) : s0;   // clamp: dummy reload on last
        #pragma unroll
        for (int q = 0; q < 4; ++q) f4[q] = *(const float4*)(Fb + (size_t)sn * ND + 4*q);
        nm_acc(sA, f, up, vp, acc);
        nm_update(up, vp, acc);
    }

    // coalesced per-lane 128 B store of (up, vp)
    float* cb = g_cbuf + (size_t)kc * 2048 + l * 32;
    #pragma unroll
    for (int q = 0; q < 4; ++q)
        *(float4*)(cb + 4*q) = make_float4(up[4*q], up[4*q+1], up[4*q+2], up[4*q+3]);
    #pragma unroll
    for (int q = 0; q < 4; ++q)
        *(float4*)(cb + 16 + 4*q) = make_float4(vp[4*q], vp[4*q+1], vp[4*q+2], vp[4*q+3]);
}

// =====================================================================
// K2: affine scan p' = Gm*p + c_k, transposed layout.
// lane (lr = l&31) holds row lr of Gm in 32 VGPRs (loaded ONCE, reused
// every iteration -- no per-iter matrix refetch at all). Wave handles 2
// batches (lb = l>>5); p broadcast via a 64-float LDS slot, wave-
// synchronous (no __syncthreads in the loop). blocks = ngroups*8
// (8 batch-octets); ~1-2 us per level.
// =====================================================================
__global__ __launch_bounds__(256, 4) void scan_k(const float* __restrict__ Gm,
                                                 float* cbase_ws, int use_gcbuf,
                                                 const float* __restrict__ seed,
                                                 float* __restrict__ totals,
                                                 int nIter)
{
    __shared__ float pb[4][64];
    float* cbase = use_gcbuf ? g_cbuf : cbase_ws;
    const int tid = threadIdx.x;
    const int w = tid >> 6, l = tid & 63;
    const int lr = l & 31, lb = l >> 5;
    const int g = blockIdx.x >> 3, o = blockIdx.x & 7;
    const int b = o*8 + w*2 + lb;

    float Gr[32];
    #pragma unroll
    for (int q = 0; q < 8; ++q) {
        float4 x = *(const float4*)(Gm + lr*32 + 4*q);
        Gr[4*q+0] = x.x; Gr[4*q+1] = x.y; Gr[4*q+2] = x.z; Gr[4*q+3] = x.w;
    }

    float pr = (seed != nullptr) ? seed[(size_t)g * 2048 + b*32 + lr] : 0.f;
    size_t coff = (size_t)g * nIter * 2048 + (size_t)(b*32 + lr);
    float cv = cbase[coff];

    for (int k = 0; k < nIter; ++k) {
        float cv_n = 0.f;
        if (k + 1 < nIter) cv_n = cbase[coff + 2048];      // prefetch next c
        if (totals == nullptr) cbase[coff] = pr;           // down-sweep: write start
        pb[w][lb*32 + lr] = pr;                            // wave-lockstep broadcast
        float n = cv;
        #pragma unroll
        for (int q = 0; q < 8; ++q) {
            float4 p4 = *(const float4*)&pb[w][lb*32 + 4*q];
            n = fmaf(Gr[4*q+0], p4.x, n);
            n = fmaf(Gr[4*q+1], p4.y, n);
            n = fmaf(Gr[4*q+2], p4.z, n);
            n = fmaf(Gr[4*q+3], p4.w, n);
        }
        pr = n; cv = cv_n; coff += 2048;
    }
    if (totals != nullptr) totals[(size_t)g * 2048 + (size_t)(b*32 + lr)] = pr;
}

// =====================================================================
// K3: outputs. 512 blocks x 256 thr; wave w owns chunk 4*blk+w; lane =
// batch. Start read from g_cbuf (down-swept); exactly 4 steps per wave,
// ZERO warm-up redundancy (was 40 steps computed per 16 useful).
// Outputs stored directly: per lane per step 3x 64 B contiguous runs ->
// full lines after write-combining.
// =====================================================================
__global__ __launch_bounds__(256, 2) void phase3_k(const float* __restrict__ F,
                                                   const float* __restrict__ ws,
                                                   float* __restrict__ out)
{
    alignas(16) __shared__ float sA[768];
    const int tid = threadIdx.x;
    for (int i = tid; i < 768; i += 256) sA[i] = ws[WS_A1T + i];
    __syncthreads();

    const int w = tid >> 6, l = tid & 63;
    const int kc = blockIdx.x * 4 + w;
    const int s0 = LCH * kc + 1;
    const int nst = min(LCH, SEQ - s0);
    const float* Fb = F + (size_t)l * BSTRIDE;

    const float* st = g_cbuf + (size_t)kc * 2048 + l * 32;
    float up[16], vp[16], acc[16];
    #pragma unroll
    for (int q = 0; q < 4; ++q) {
        float4 x = *(const float4*)(st + 4*q);
        up[4*q+0] = x.x; up[4*q+1] = x.y; up[4*q+2] = x.z; up[4*q+3] = x.w;
    }
    #pragma unroll
    for (int q = 0; q < 4; ++q) {
        float4 x = *(const float4*)(st + 16 + 4*q);
        vp[4*q+0] = x.x; vp[4*q+1] = x.y; vp[4*q+2] = x.z; vp[4*q+3] = x.w;
    }

    float4 f4[4];
    #pragma unroll
    for (int q = 0; q < 4; ++q) f4[q] = *(const float4*)(Fb + (size_t)s0 * ND + 4*q);

    float* gu = out + UOFF + (size_t)l * BSTRIDE + (size_t)s0 * ND;
    float* gv = out + VOFF + (size_t)l * BSTRIDE + (size_t)s0 * ND;
    float* ga = out + AOFF + (size_t)l * BSTRIDE + (size_t)s0 * ND;

    for (int i = 0; i < nst; ++i) {
        float f[16];
        #pragma unroll
        for (int q = 0; q < 4; ++q) {
            f[4*q+0] = f4[q].x; f[4*q+1] = f4[q].y; f[4*q+2] = f4[q].z; f[4*q+3] = f4[q].w;
        }
        const int sn = (i + 1 < nst) ? (s0 + i + 1) : s0;
        #pragma unroll
        for (int q = 0; q < 4; ++q) f4[q] = *(const float4*)(Fb + (size_t)sn * ND + 4*q);

        nm_acc(sA, f, up, vp, acc);

        // outputs from pre-update state: u_n = up + C3*acc, v_n = vp + C4*acc, a_n = acc
        #pragma unroll
        for (int q = 0; q < 4; ++q) {
            float4 u4, v4, a4;
            u4.x = fmaf(C3, acc[4*q+0], up[4*q+0]);
            u4.y = fmaf(C3, acc[4*q+1], up[4*q+1]);
            u4.z = fmaf(C3, acc[4*q+2], up[4*q+2]);
            u4.w = fmaf(C3, acc[4*q+3], up[4*q+3]);
            v4.x = fmaf(C4, acc[4*q+0], vp[4*q+0]);
            v4.y = fmaf(C4, acc[4*q+1], vp[4*q+1]);
            v4.z = fmaf(C4, acc[4*q+2], vp[4*q+2]);
            v4.w = fmaf(C4, acc[4*q+3], vp[4*q+3]);
            a4.x = acc[4*q+0]; a4.y = acc[4*q+1]; a4.z = acc[4*q+2]; a4.w = acc[4*q+3];
            *(float4*)(gu + (size_t)i * ND + 4*q) = u4;
            *(float4*)(gv + (size_t)i * ND + 4*q) = v4;
            *(float4*)(ga + (size_t)i * ND + 4*q) = a4;
        }
        nm_update(up, vp, acc);
    }
}

// =====================================================================
// Hierarchy: 2048 4-step chunks, radix-8:
//   L1 up (G4): 2048 -> 256   L2 up (G32): 256 -> 32
//   L3 up (G256): 32 -> 4     L4 (G2048, seed p1, nIter=4): starts in T3
//   then down-sweep L3d, L2d, L1d -> per-chunk starts in g_cbuf.
// Tail chunk (3 steps) is safe: its (mis-)combined total only feeds
// prefixes of later chunks, of which there are none.
// =====================================================================
extern "C" void kernel_launch(void* const* d_in, const int* in_sizes, int n_in,
                              void* d_out, int out_size, void* d_ws, size_t ws_size,
                              hipStream_t stream)
{
    const float* F = (const float*)d_in[0];
    const float* M = (const float*)d_in[1];
    const float* C = (const float*)d_in[2];
    const float* K = (const float*)d_in[3];
    float* out = (float*)d_out;
    float* ws  = (float*)d_ws;

    setup_k <<<1,   512, 0, stream>>>(F, M, C, K, ws, out);
    phase1_k<<<512, 256, 0, stream>>>(F, ws);
    scan_k<<<2048, 256, 0, stream>>>(ws + WS_G4,   nullptr,     1, nullptr,      ws + WS_T1, 8);
    scan_k<<<256,  256, 0, stream>>>(ws + WS_G32,  ws + WS_T1,  0, nullptr,      ws + WS_T2, 8);
    scan_k<<<32,   256, 0, stream>>>(ws + WS_G256, ws + WS_T2,  0, nullptr,      ws + WS_T3, 8);
    scan_k<<<8,    256, 0, stream>>>(ws + WS_G2048,ws + WS_T3,  0, ws + WS_P1,   nullptr,    4);
    scan_k<<<32,   256, 0, stream>>>(ws + WS_G256, ws + WS_T2,  0, ws + WS_T3,   nullptr,    8);
    scan_k<<<256,  256, 0, stream>>>(ws + WS_G32,  ws + WS_T1,  0, ws + WS_T2,   nullptr,    8);
    scan_k<<<2048, 256, 0, stream>>>(ws + WS_G4,   nullptr,     1, ws + WS_T1,   nullptr,    8);
    phase3_k<<<512, 256, 0, stream>>>(F, ws, out);
}

// Round 3
// 900.751 us; speedup vs baseline: 1.1051x; 1.1051x over previous
//
#include <hip/hip_runtime.h>
#include <stdint.h>

// ---------------- problem constants ----------------
constexpr int   SEQ  = 8192;
constexpr int   NB   = 64;
constexpr int   ND   = 16;
constexpr float DT    = 0.01f;
constexpr float BETA  = 0.25f;
constexpr float GAMMA = 0.5f;
constexpr float C1 = (0.5f - BETA) * DT * DT;
constexpr float C2 = (1.0f - GAMMA) * DT;
constexpr float C3 = BETA * DT * DT;
constexpr float C4 = GAMMA * DT;
constexpr float E1 = C1 + C3 + DT * C4;   // up' = up + DT*vp + E1*acc
constexpr float E2 = C2 + C4;             // vp' = vp + E2*acc
constexpr float GDT  = GAMMA * DT;
constexpr float BDT2 = BETA * DT * DT;

constexpr int LCH = 4;        // scan chunk = 4 steps
constexpr int NCH = 2048;     // chunks over steps 1..8191 (last has 3)
constexpr size_t BSTRIDE = (size_t)SEQ * ND;
constexpr size_t UOFF = 0;
constexpr size_t VOFF = (size_t)NB * SEQ * ND;
constexpr size_t AOFF = 2 * VOFF;

// ws layout (float offsets), ~2.4 MB
constexpr int WS_A1T   = 0;                    // 768: A1^T,A2^T,A3^T (j*16+d)
constexpr int WS_G4    = 768;                  // 1024 each, 32x32 row-major
constexpr int WS_G32   = 1792;
constexpr int WS_G256  = 2816;
constexpr int WS_G2048 = 3840;
constexpr int WS_P1    = 4864;                 // 2048: state entering step1, [r*64+b]
constexpr int WS_T1    = 8192;                 // 256 * 2048
constexpr int WS_T2    = WS_T1 + 256 * 2048;   // 32  * 2048
constexpr int WS_T3    = WS_T2 + 32 * 2048;    // 4   * 2048

// 4-step chunk totals (up-sweep) -> chunk starts (down-sweep).
// Layout: [chunk][r*64 + b], rows 0..15 = up, 16..31 = vp  (256 B-contiguous
// per-instruction access everywhere -- the round-1 [b*32+r] layout caused
// ~20x HBM write/read amplification).
__device__ float g_cbuf[(size_t)NCH * 2048];

// =====================================================================
// Newmark core: acc = A1*f - A3*up - A2*vp; matrices broadcast from LDS.
// =====================================================================
__device__ __forceinline__ void nm_acc(const float* __restrict__ sA,
                                       const float f[16], const float up[16],
                                       const float vp[16], float acc[16])
{
    #pragma unroll
    for (int d = 0; d < 16; ++d) acc[d] = 0.f;
    #pragma unroll
    for (int j = 0; j < 16; ++j) {
        const float fj = f[j];
        const float nu = -up[j];
        const float nv = -vp[j];
        #pragma unroll
        for (int q = 0; q < 4; ++q) {
            const float4 m1 = *(const float4*)(sA +       j*16 + 4*q);
            const float4 m2 = *(const float4*)(sA + 256 + j*16 + 4*q);
            const float4 m3 = *(const float4*)(sA + 512 + j*16 + 4*q);
            acc[4*q+0] = fmaf(m1.x, fj, acc[4*q+0]);
            acc[4*q+0] = fmaf(m3.x, nu, acc[4*q+0]);
            acc[4*q+0] = fmaf(m2.x, nv, acc[4*q+0]);
            acc[4*q+1] = fmaf(m1.y, fj, acc[4*q+1]);
            acc[4*q+1] = fmaf(m3.y, nu, acc[4*q+1]);
            acc[4*q+1] = fmaf(m2.y, nv, acc[4*q+1]);
            acc[4*q+2] = fmaf(m1.z, fj, acc[4*q+2]);
            acc[4*q+2] = fmaf(m3.z, nu, acc[4*q+2]);
            acc[4*q+2] = fmaf(m2.z, nv, acc[4*q+2]);
            acc[4*q+3] = fmaf(m1.w, fj, acc[4*q+3]);
            acc[4*q+3] = fmaf(m3.w, nu, acc[4*q+3]);
            acc[4*q+3] = fmaf(m2.w, nv, acc[4*q+3]);
        }
    }
}

__device__ __forceinline__ void nm_update(float up[16], float vp[16], const float acc[16])
{
    #pragma unroll
    for (int d = 0; d < 16; ++d) {
        up[d] = fmaf(DT, vp[d], up[d]);
        up[d] = fmaf(E1, acc[d], up[d]);
        vp[d] = fmaf(E2, acc[d], vp[d]);
    }
}

// ---------------------------------------------------------------------
// Stage 8 steps of the block's F tile into LDS, XOR-swizzled.
// Per instruction: 2 batches x 512 B fully contiguous (proven pattern).
// sF[b*128 + (W ^ (b&31))], W = step_in_half*16 + d.
// ---------------------------------------------------------------------
__device__ __forceinline__ void stage_half(const float* __restrict__ F, float* __restrict__ sF,
                                           int l, int w, int s0b, int nstB, int h)
{
    const int lw  = l & 31;
    const int sin = lw >> 2;
    const bool valid = (8*h + sin) < nstB;
    const int W0 = 4*lw;
    #pragma unroll
    for (int p = 0; p < 8; ++p) {
        const int b = p*8 + w*2 + (l >> 5);
        float4 x = make_float4(0.f,0.f,0.f,0.f);
        if (valid) x = *(const float4*)(F + (size_t)b * BSTRIDE + (size_t)(s0b + 8*h) * ND + W0);
        const int cb = b & 31;
        sF[b*128 + ((W0+0) ^ cb)] = x.x;
        sF[b*128 + ((W0+1) ^ cb)] = x.y;
        sF[b*128 + ((W0+2) ^ cb)] = x.z;
        sF[b*128 + ((W0+3) ^ cb)] = x.w;
    }
}

// ---------------------------------------------------------------------
// Drain one array's 4-step group: per instruction 4 batches x 256 B.
// so layout: so[b*64 + (e ^ (b&31))], e = step_in_chunk*16 + d.
// ---------------------------------------------------------------------
__device__ __forceinline__ void drain_arr(const float* __restrict__ so_w,
                                          float* __restrict__ gbase,
                                          int l, int nstc)
{
    const int m = l & 15, dlt = l >> 4;
    const bool ok = (m >> 2) < nstc;
    #pragma unroll
    for (int g = 0; g < 16; ++g) {
        const int b = g*4 + dlt;
        const int cb = b & 31;
        float4 x;
        x.x = so_w[b*64 + ((4*m+0) ^ cb)];
        x.y = so_w[b*64 + ((4*m+1) ^ cb)];
        x.z = so_w[b*64 + ((4*m+2) ^ cb)];
        x.w = so_w[b*64 + ((4*m+3) ^ cb)];
        if (ok) *(float4*)(gbase + (size_t)b * BSTRIDE + 4*m) = x;
    }
}

// =====================================================================
// K0: inverses, A1/A2/A3 (transposed), G powers {4,32,256,2048}, p1
// seed, step-0 outputs. One block, 512 threads.
// =====================================================================
__global__ __launch_bounds__(512) void setup_k(const float* __restrict__ F,
                                               const float* __restrict__ Mg,
                                               const float* __restrict__ Cg,
                                               const float* __restrict__ Kg,
                                               float* __restrict__ ws,
                                               float* __restrict__ out)
{
    __shared__ float sM[256], sC[256], sK[256];
    __shared__ float aug[16][33];
    __shared__ float A1s[256], A2s[256], A3s[256], Mis[256];
    __shared__ float bA[1024], bB[1024];
    const int tid = threadIdx.x;
    if (tid < 256) { sM[tid] = Mg[tid]; sC[tid] = Cg[tid]; sK[tid] = Kg[tid]; }
    __syncthreads();

    const int r = tid >> 5, c = tid & 31;
    {
        float v;
        if (c < 16) v = sM[r*16+c] + GDT * sC[r*16+c] + BDT2 * sK[r*16+c];
        else        v = (c - 16 == r) ? 1.f : 0.f;
        aug[r][c] = v;
    }
    __syncthreads();
    for (int kk = 0; kk < 16; ++kk) {
        float pv   = aug[kk][kk];
        float fr   = aug[r][kk];
        float akc  = aug[kk][c];
        float curv = aug[r][c];
        __syncthreads();
        float inv = 1.0f / pv;
        aug[r][c] = (r == kk) ? curv * inv : fmaf(-fr * inv, akc, curv);
        __syncthreads();
    }
    if (tid < 256) A1s[tid] = aug[tid >> 4][(tid & 15) + 16];
    __syncthreads();

    aug[r][c] = (c < 16) ? sM[r*16+c] : ((c - 16 == r) ? 1.f : 0.f);
    __syncthreads();
    for (int kk = 0; kk < 16; ++kk) {
        float pv   = aug[kk][kk];
        float fr   = aug[r][kk];
        float akc  = aug[kk][c];
        float curv = aug[r][c];
        __syncthreads();
        float inv = 1.0f / pv;
        aug[r][c] = (r == kk) ? curv * inv : fmaf(-fr * inv, akc, curv);
        __syncthreads();
    }
    if (tid < 256) Mis[tid] = aug[tid >> 4][(tid & 15) + 16];
    __syncthreads();

    if (tid < 256) {
        const int rr = tid >> 4, cc = tid & 15;
        float a2 = 0.f, a3 = 0.f;
        #pragma unroll
        for (int j = 0; j < 16; ++j) {
            const float a = A1s[rr*16+j];
            a2 = fmaf(a, sC[j*16+cc], a2);
            a3 = fmaf(a, sK[j*16+cc], a3);
        }
        A2s[tid] = a2; A3s[tid] = a3;
    }
    __syncthreads();

    if (tid < 256) {
        const int j = tid >> 4, d = tid & 15;
        ws[WS_A1T +       tid] = A1s[d*16+j];
        ws[WS_A1T + 256 + tid] = A2s[d*16+j];
        ws[WS_A1T + 512 + tid] = A3s[d*16+j];
    }
    for (int idx = tid; idx < 1024; idx += 512) {
        const int i = idx >> 5, j = idx & 31;
        float v;
        if (i < 16) {
            if (j < 16) v = ((i == j) ? 1.f : 0.f) - E1 * A3s[i*16+j];
            else        v = ((i == j - 16) ? DT : 0.f) - E1 * A2s[i*16+(j-16)];
        } else {
            const int i2 = i - 16;
            if (j < 16) v = -E2 * A3s[i2*16+j];
            else        v = ((i2 == j - 16) ? 1.f : 0.f) - E2 * A2s[i2*16+(j-16)];
        }
        bA[idx] = v;
    }
    __syncthreads();
    // after iter s: bA = G^(2^(s+1)); store G4 (s=1), G32 (s=4), G256 (s=7), G2048 (end)
    for (int s = 0; s < 11; ++s) {
        for (int idx = tid; idx < 1024; idx += 512) {
            const int i = idx >> 5, j = idx & 31;
            float acc = 0.f;
            #pragma unroll
            for (int q = 0; q < 32; ++q) acc = fmaf(bA[i*32+q], bA[q*32+j], acc);
            bB[idx] = acc;
        }
        __syncthreads();
        for (int idx = tid; idx < 1024; idx += 512) bA[idx] = bB[idx];
        __syncthreads();
        if (s == 1) for (int idx = tid; idx < 1024; idx += 512) ws[WS_G4   + idx] = bA[idx];
        if (s == 4) for (int idx = tid; idx < 1024; idx += 512) ws[WS_G32  + idx] = bA[idx];
        if (s == 7) for (int idx = tid; idx < 1024; idx += 512) ws[WS_G256 + idx] = bA[idx];
    }
    for (int idx = tid; idx < 1024; idx += 512) ws[WS_G2048 + idx] = bA[idx];

    // step-0 outputs + p1 seed (state entering step 1): up=C1*a0, vp=C2*a0
    for (int t = tid; t < 1024; t += 512) {
        const int b = t >> 4, d = t & 15;
        float s0 = 0.f;
        #pragma unroll
        for (int j = 0; j < 16; ++j) s0 = fmaf(Mis[d*16+j], F[(size_t)b * BSTRIDE + j], s0);
        out[UOFF + (size_t)b * BSTRIDE + d] = 0.f;
        out[VOFF + (size_t)b * BSTRIDE + d] = 0.f;
        out[AOFF + (size_t)b * BSTRIDE + d] = s0;
        ws[WS_P1 + d*64 + b]        = C1 * s0;
        ws[WS_P1 + (16 + d)*64 + b] = C2 * s0;
    }
}

// =====================================================================
// K1: 4-step chunk totals from zero state. 512 blocks x 256 thr; block
// tile = 16 steps staged in two 8-step halves (coalesced); wave w owns
// chunk 4*blk+w; lane = batch. Totals stored [r*64+b] (256 B/instr).
// =====================================================================
__global__ __launch_bounds__(256, 2) void phase1_k(const float* __restrict__ F,
                                                   const float* __restrict__ ws)
{
    alignas(16) __shared__ float sA[768];
    __shared__ float sF[64*128];   // 32 KB (one half)
    const int tid = threadIdx.x;
    for (int i = tid; i < 768; i += 256) sA[i] = ws[WS_A1T + i];
    const int w = tid >> 6, l = tid & 63;
    const int blk = blockIdx.x;
    const int s0b = 16*blk + 1;
    const int nstB = min(16, SEQ - s0b);
    const int kc = blk*4 + w;
    const int c = l & 31;

    float up[16], vp[16], acc[16];
    #pragma unroll
    for (int d = 0; d < 16; ++d) { up[d] = 0.f; vp[d] = 0.f; }

    stage_half(F, sF, l, w, s0b, nstB, 0);
    __syncthreads();
    if (w < 2) {
        #pragma unroll
        for (int i = 0; i < 4; ++i) {
            const int t = 4*w + i;          // 0..7, always < nstB (>=15)
            float f[16];
            #pragma unroll
            for (int d = 0; d < 16; ++d) f[d] = sF[l*128 + ((((t&7)*16) + d) ^ c)];
            nm_acc(sA, f, up, vp, acc);
            nm_update(up, vp, acc);
        }
    }
    __syncthreads();
    stage_half(F, sF, l, w, s0b, nstB, 1);
    __syncthreads();
    if (w >= 2) {
        #pragma unroll
        for (int i = 0; i < 4; ++i) {
            const int t = 4*w + i;          // 8..15
            if (t < nstB) {
                float f[16];
                #pragma unroll
                for (int d = 0; d < 16; ++d) f[d] = sF[l*128 + ((((t&7)*16) + d) ^ c)];
                nm_acc(sA, f, up, vp, acc);
                nm_update(up, vp, acc);
            }
        }
    }
    float* cb = g_cbuf + (size_t)kc * 2048;
    #pragma unroll
    for (int d = 0; d < 16; ++d) { cb[d*64 + l] = up[d]; cb[(16+d)*64 + l] = vp[d]; }
}

// =====================================================================
// K2: affine scan p' = Gm*p + c_k. Layout [r*64+b] throughout.
// G staged in LDS once (broadcast float4 reads); p double-buffered in
// LDS; c_k read BEFORE the down-sweep start-overwrite.
// =====================================================================
__global__ __launch_bounds__(256, 4) void scan_k(const float* __restrict__ Gm,
                                                 float* cbase_ws, int use_gcbuf,
                                                 const float* __restrict__ seed,
                                                 float* __restrict__ totals,
                                                 int nIter)
{
    alignas(16) __shared__ float sG[1024];
    __shared__ float pb[2][2048];
    float* cbase = use_gcbuf ? g_cbuf : cbase_ws;
    const int tid = threadIdx.x;
    const int b = tid & 63;
    const int w = tid >> 6;
    const int g = blockIdx.x;
    for (int i = tid; i < 1024; i += 256) sG[i] = Gm[i];

    float pr[8];
    #pragma unroll
    for (int q = 0; q < 8; ++q) {
        const int r = w + 4*q;
        pr[q] = (seed != nullptr) ? seed[(size_t)g * 2048 + r*64 + b] : 0.f;
        pb[0][r*64 + b] = pr[q];
    }
    __syncthreads();
    int cur = 0;
    float* cslot = cbase + (size_t)g * nIter * 2048;
    for (int k = 0; k < nIter; ++k) {
        float n[8];
        #pragma unroll
        for (int q = 0; q < 8; ++q) n[q] = cslot[(w + 4*q)*64 + b];       // c_k
        if (totals == nullptr) {
            #pragma unroll
            for (int q = 0; q < 8; ++q) cslot[(w + 4*q)*64 + b] = pr[q];  // write start
        }
        #pragma unroll
        for (int j4 = 0; j4 < 8; ++j4) {
            const float p0 = pb[cur][(4*j4+0)*64 + b];
            const float p1 = pb[cur][(4*j4+1)*64 + b];
            const float p2 = pb[cur][(4*j4+2)*64 + b];
            const float p3 = pb[cur][(4*j4+3)*64 + b];
            #pragma unroll
            for (int q = 0; q < 8; ++q) {
                const float4 gq = *(const float4*)&sG[(w + 4*q)*32 + 4*j4];
                n[q] = fmaf(gq.x, p0, n[q]);
                n[q] = fmaf(gq.y, p1, n[q]);
                n[q] = fmaf(gq.z, p2, n[q]);
                n[q] = fmaf(gq.w, p3, n[q]);
            }
        }
        #pragma unroll
        for (int q = 0; q < 8; ++q) { pr[q] = n[q]; pb[cur ^ 1][(w + 4*q)*64 + b] = n[q]; }
        cur ^= 1;
        cslot += 2048;
        __syncthreads();
    }
    if (totals != nullptr) {
        #pragma unroll
        for (int q = 0; q < 8; ++q) totals[(size_t)g * 2048 + (w + 4*q)*64 + b] = pr[q];
    }
}

// =====================================================================
// K3: outputs. 512 blocks x 256 thr; wave w owns chunk 4*blk+w; start
// from down-swept g_cbuf; exactly 4 steps/wave, zero redundancy.
// Outputs staged in so (XOR-swizzled) and drained 256 B/instr.
// =====================================================================
__global__ __launch_bounds__(256, 2) void phase3_k(const float* __restrict__ F,
                                                   const float* __restrict__ ws,
                                                   float* __restrict__ out)
{
    alignas(16) __shared__ float sA[768];
    __shared__ float sF[64*128];     // 32 KB
    __shared__ float so[2][4096];    // 32 KB: 2 concurrently-draining waves
    const int tid = threadIdx.x;
    for (int i = tid; i < 768; i += 256) sA[i] = ws[WS_A1T + i];
    const int w = tid >> 6, l = tid & 63;
    const int blk = blockIdx.x;
    const int s0b = 16*blk + 1;
    const int nstB = min(16, SEQ - s0b);
    const int kc = blk*4 + w;
    const int s0c = s0b + 4*w;
    const int nstc = min(LCH, SEQ - s0c);
    const int c = l & 31;

    // start state (coalesced 256 B/instr reads; overlaps staging latency)
    const float* st = g_cbuf + (size_t)kc * 2048;
    float up[16], vp[16], acc[16];
    #pragma unroll
    for (int d = 0; d < 16; ++d) { up[d] = st[d*64 + l]; vp[d] = st[(16+d)*64 + l]; }

    float vo[4][16], ao[4][16];
    float* so_w = &so[w & 1][0];
    float* gu = out + UOFF + (size_t)s0c * ND;
    float* gv = out + VOFF + (size_t)s0c * ND;
    float* ga = out + AOFF + (size_t)s0c * ND;

    stage_half(F, sF, l, w, s0b, nstB, 0);
    __syncthreads();
    if (w < 2) {
        #pragma unroll
        for (int i = 0; i < 4; ++i) {
            const int t = 4*w + i;          // 0..7, always valid
            float f[16];
            #pragma unroll
            for (int d = 0; d < 16; ++d) f[d] = sF[l*128 + ((((t&7)*16) + d) ^ c)];
            nm_acc(sA, f, up, vp, acc);
            #pragma unroll
            for (int d = 0; d < 16; ++d) {
                so_w[l*64 + ((i*16+d) ^ c)] = fmaf(C3, acc[d], up[d]);
                vo[i][d] = fmaf(C4, acc[d], vp[d]);
                ao[i][d] = acc[d];
            }
            nm_update(up, vp, acc);
        }
        drain_arr(so_w, gu, l, nstc);
        #pragma unroll
        for (int i = 0; i < 4; ++i)
            #pragma unroll
            for (int d = 0; d < 16; ++d) so_w[l*64 + ((i*16+d) ^ c)] = vo[i][d];
        drain_arr(so_w, gv, l, nstc);
        #pragma unroll
        for (int i = 0; i < 4; ++i)
            #pragma unroll
            for (int d = 0; d < 16; ++d) so_w[l*64 + ((i*16+d) ^ c)] = ao[i][d];
        drain_arr(so_w, ga, l, nstc);
    }
    __syncthreads();
    stage_half(F, sF, l, w, s0b, nstB, 1);
    __syncthreads();
    if (w >= 2) {
        #pragma unroll
        for (int i = 0; i < 4; ++i) {
            const int t = 4*w + i;          // 8..15
            if (t < nstB) {
                float f[16];
                #pragma unroll
                for (int d = 0; d < 16; ++d) f[d] = sF[l*128 + ((((t&7)*16) + d) ^ c)];
                nm_acc(sA, f, up, vp, acc);
                #pragma unroll
                for (int d = 0; d < 16; ++d) {
                    so_w[l*64 + ((i*16+d) ^ c)] = fmaf(C3, acc[d], up[d]);
                    vo[i][d] = fmaf(C4, acc[d], vp[d]);
                    ao[i][d] = acc[d];
                }
                nm_update(up, vp, acc);
            }
        }
        drain_arr(so_w, gu, l, nstc);
        #pragma unroll
        for (int i = 0; i < 4; ++i)
            #pragma unroll
            for (int d = 0; d < 16; ++d) so_w[l*64 + ((i*16+d) ^ c)] = vo[i][d];
        drain_arr(so_w, gv, l, nstc);
        #pragma unroll
        for (int i = 0; i < 4; ++i)
            #pragma unroll
            for (int d = 0; d < 16; ++d) so_w[l*64 + ((i*16+d) ^ c)] = ao[i][d];
        drain_arr(so_w, ga, l, nstc);
    }
}

// =====================================================================
// Hierarchy: 2048 4-step chunks, radix-8:
//   up:  G4 (256 grps) -> G32 (32) -> G256 (4) -> top G2048 (1 grp, 4 it,
//        seeded by P1, writes starts into T3)
//   down: G256 -> G32 -> G4 (starts into g_cbuf)
// Tail chunk (3 steps): its mis-sized total only feeds prefixes of later
// chunks, of which there are none.
// =====================================================================
extern "C" void kernel_launch(void* const* d_in, const int* in_sizes, int n_in,
                              void* d_out, int out_size, void* d_ws, size_t ws_size,
                              hipStream_t stream)
{
    const float* F = (const float*)d_in[0];
    const float* M = (const float*)d_in[1];
    const float* C = (const float*)d_in[2];
    const float* K = (const float*)d_in[3];
    float* out = (float*)d_out;
    float* ws  = (float*)d_ws;

    setup_k <<<1,   512, 0, stream>>>(F, M, C, K, ws, out);
    phase1_k<<<512, 256, 0, stream>>>(F, ws);
    scan_k<<<256, 256, 0, stream>>>(ws + WS_G4,   nullptr,    1, nullptr,    ws + WS_T1, 8);
    scan_k<<<32,  256, 0, stream>>>(ws + WS_G32,  ws + WS_T1, 0, nullptr,    ws + WS_T2, 8);
    scan_k<<<4,   256, 0, stream>>>(ws + WS_G256, ws + WS_T2, 0, nullptr,    ws + WS_T3, 8);
    scan_k<<<1,   256, 0, stream>>>(ws + WS_G2048,ws + WS_T3, 0, ws + WS_P1, nullptr,    4);
    scan_k<<<4,   256, 0, stream>>>(ws + WS_G256, ws + WS_T2, 0, ws + WS_T3, nullptr,    8);
    scan_k<<<32,  256, 0, stream>>>(ws + WS_G32,  ws + WS_T1, 0, ws + WS_T2, nullptr,    8);
    scan_k<<<256, 256, 0, stream>>>(ws + WS_G4,   nullptr,    1, ws + WS_T1, nullptr,    8);
    phase3_k<<<512, 256, 0, stream>>>(F, ws, out);
}